// Round 2
// baseline (2613.099 us; speedup 1.0000x reference)
//
#include <hip/hip_runtime.h>
#include <hip/hip_bf16.h>
#include <cstdint>

typedef __bf16 bf16_t;
typedef __attribute__((ext_vector_type(8))) __bf16 bf16x8;
typedef __attribute__((ext_vector_type(4))) float f32x4;

#define S_LEN 2048
#define NHEADS 16
#define DK 64
#define DMODEL 1024
#define BATCH 4

__device__ __forceinline__ bf16x8 ld8(const bf16_t* p) { return *(const bf16x8*)p; }

__device__ __forceinline__ bf16x8 cvt8(const float* p) {
    f32x4 a = *(const f32x4*)p;
    f32x4 b = *(const f32x4*)(p + 4);
    bf16x8 r;
    r[0] = (bf16_t)a[0]; r[1] = (bf16_t)a[1]; r[2] = (bf16_t)a[2]; r[3] = (bf16_t)a[3];
    r[4] = (bf16_t)b[0]; r[5] = (bf16_t)b[1]; r[6] = (bf16_t)b[2]; r[7] = (bf16_t)b[3];
    return r;
}

// ---------------- fp32 -> bf16 convert (weights) ----------------
__global__ __launch_bounds__(256) void cvt_kernel(const float* __restrict__ in,
                                                  bf16_t* __restrict__ out) {
    int i = (blockIdx.x * 256 + threadIdx.x) * 8;
    *(bf16x8*)(out + i) = cvt8(in + i);
}

// ---------------- mask bit-pack: (B,S,S) int32 -> bit per element ----------------
__global__ __launch_bounds__(256) void pack_mask_kernel(const int* __restrict__ mask,
                                                        unsigned long long* __restrict__ bits) {
    size_t idx = (size_t)blockIdx.x * 256 + threadIdx.x;
    int v = mask[idx];
    unsigned long long b = __ballot(v != 0);
    if ((threadIdx.x & 63) == 0) bits[idx >> 6] = b;
}

// ---------------- proj GEMM: Y = X @ W^T + bias ----------------
// X: (M,1024) fp32 (A32) or bf16, W: (1024,1024) bf16 [N][K], bias fp32
// mode 0: write (B,H,S,64)  mode 1: write (B,H,64,S)  mode 2: plain (M,1024)
template <bool A32>
__global__ __launch_bounds__(256) void gemm_proj(
    const void* __restrict__ Xv, const bf16_t* __restrict__ W,
    const float* __restrict__ bias, bf16_t* __restrict__ Y, int mode)
{
    const int K = DMODEL;
    int lane = threadIdx.x & 63;
    int wave = threadIdx.x >> 6;
    int lr = lane & 15, lg = lane >> 4;
    int i0 = blockIdx.x * 64 + wave * 16;   // 16 rows per wave
    int j0 = blockIdx.y * 64;               // 64 cols per block
    const float*  xf = (const float*)Xv  + (size_t)(i0 + lr) * K + lg * 8;
    const bf16_t* xh = (const bf16_t*)Xv + (size_t)(i0 + lr) * K + lg * 8;
    const bf16_t* wp = W + (size_t)(j0 + lr) * K + lg * 8;
    f32x4 acc[4] = {};
    for (int kk = 0; kk < K; kk += 32) {
        bf16x8 a = A32 ? cvt8(xf + kk) : ld8(xh + kk);
        #pragma unroll
        for (int nt = 0; nt < 4; ++nt) {
            bf16x8 bf = ld8(wp + (size_t)(nt * 16) * K + kk);
            acc[nt] = __builtin_amdgcn_mfma_f32_16x16x32_bf16(a, bf, acc[nt], 0, 0, 0);
        }
    }
    #pragma unroll
    for (int nt = 0; nt < 4; ++nt) {
        int col = j0 + nt * 16 + lr;
        float bv = bias[col];
        #pragma unroll
        for (int r = 0; r < 4; ++r) {
            int row = i0 + lg * 4 + r;   // C/D: col=lane&15, row=(lane>>4)*4+reg
            float v = acc[nt][r] + bv;
            size_t off;
            if (mode == 2) {
                off = (size_t)row * DMODEL + col;
            } else {
                int b = row >> 11, s = row & (S_LEN - 1);
                int h = col >> 6, d = col & (DK - 1);
                if (mode == 0) off = ((size_t)(b * NHEADS + h) * S_LEN + s) * DK + d;
                else           off = ((size_t)(b * NHEADS + h) * DK + d) * S_LEN + s;
            }
            Y[off] = (bf16_t)v;
        }
    }
}

// ---------------- fused attention ----------------
// qb,kb: (B*H,S,64) bf16  vT: (B*H,64,S) bf16  mbits: (B,S,S/64)
// attn_out: (B,H,S,S) fp32   ctx_out: (B,S,1024) bf16
__global__ __launch_bounds__(256) void attn_kernel(
    const bf16_t* __restrict__ qb, const bf16_t* __restrict__ kb,
    const bf16_t* __restrict__ vT, const unsigned long long* __restrict__ mbits,
    float* __restrict__ attn_out, bf16_t* __restrict__ ctx_out)
{
    __shared__ __align__(16) float psharef[4][16][68];
    int lane = threadIdx.x & 63;
    int wave = threadIdx.x >> 6;
    int lr = lane & 15, lg = lane >> 4;
    int bh = blockIdx.x >> 5;
    int b = bh >> 4, h = bh & (NHEADS - 1);
    int q0 = (blockIdx.x & 31) * 64 + wave * 16;   // this wave's 16 query rows

    const bf16_t* qp = qb + ((size_t)bh * S_LEN + q0 + lr) * DK + lg * 8;
    bf16x8 aq0 = ld8(qp), aq1 = ld8(qp + 32);

    const bf16_t* kp = kb + ((size_t)bh * S_LEN + lr) * DK + lg * 8;
    const unsigned long long* mp = mbits + ((size_t)b * S_LEN + q0 + lg * 4) * (S_LEN / 64);

    float m[4] = {-1e30f, -1e30f, -1e30f, -1e30f};
    float l[4] = {0.f, 0.f, 0.f, 0.f};

    // ---- pass 1: online row max + exp-sum ----
    for (int n0 = 0; n0 < S_LEN; n0 += 64) {
        f32x4 sc[4];
        #pragma unroll
        for (int nt = 0; nt < 4; ++nt) {
            const bf16_t* kr = kp + (size_t)(n0 + nt * 16) * DK;
            f32x4 c = {0.f, 0.f, 0.f, 0.f};
            c = __builtin_amdgcn_mfma_f32_16x16x32_bf16(aq0, ld8(kr), c, 0, 0, 0);
            c = __builtin_amdgcn_mfma_f32_16x16x32_bf16(aq1, ld8(kr + 32), c, 0, 0, 0);
            sc[nt] = c;
        }
        int w = n0 >> 6;
        #pragma unroll
        for (int r = 0; r < 4; ++r) {
            unsigned long long mw = mp[r * (S_LEN / 64) + w];
            float sv[4];
            float mx = -1e30f;
            #pragma unroll
            for (int nt = 0; nt < 4; ++nt) {
                float s = sc[nt][r] * 0.125f;
                if (!((mw >> (nt * 16 + lr)) & 1ULL)) s = -1e9f;
                sv[nt] = s;
                mx = fmaxf(mx, s);
            }
            #pragma unroll
            for (int off = 1; off < 16; off <<= 1) mx = fmaxf(mx, __shfl_xor(mx, off, 64));
            float mn = fmaxf(m[r], mx);
            float sum = 0.f;
            #pragma unroll
            for (int nt = 0; nt < 4; ++nt) sum += __expf(sv[nt] - mn);
            #pragma unroll
            for (int off = 1; off < 16; off <<= 1) sum += __shfl_xor(sum, off, 64);
            l[r] = l[r] * __expf(m[r] - mn) + sum;
            m[r] = mn;
        }
    }
    float inv_l[4];
    #pragma unroll
    for (int r = 0; r < 4; ++r) inv_l[r] = 1.f / l[r];

    // ---- pass 2: recompute scores, write normalized attn (fp32), accumulate P@V ----
    f32x4 ctx[4] = {};
    size_t attn_base = ((size_t)bh * S_LEN + q0) * S_LEN;
    for (int n0 = 0; n0 < S_LEN; n0 += 64) {
        int w = n0 >> 6;
        #pragma unroll
        for (int nt = 0; nt < 4; ++nt) {
            const bf16_t* kr = kp + (size_t)(n0 + nt * 16) * DK;
            f32x4 c = {0.f, 0.f, 0.f, 0.f};
            c = __builtin_amdgcn_mfma_f32_16x16x32_bf16(aq0, ld8(kr), c, 0, 0, 0);
            c = __builtin_amdgcn_mfma_f32_16x16x32_bf16(aq1, ld8(kr + 32), c, 0, 0, 0);
            #pragma unroll
            for (int r = 0; r < 4; ++r) {
                unsigned long long mw = mp[r * (S_LEN / 64) + w];
                float s = c[r] * 0.125f;
                if (!((mw >> (nt * 16 + lr)) & 1ULL)) s = -1e9f;
                float p = __expf(s - m[r]) * inv_l[r];
                psharef[wave][lg * 4 + r][nt * 16 + lr] = p;   // C-layout -> LDS
            }
        }
        __syncthreads();
        // coalesced fp32 attn store: 4 full rows per float4-instruction
        #pragma unroll
        for (int j = 0; j < 4; ++j) {
            int flat = j * 64 + lane;
            int rr = flat >> 4, cc = (flat & 15) * 4;
            *(f32x4*)(attn_out + attn_base + (size_t)rr * S_LEN + n0 + cc) =
                *(const f32x4*)&psharef[wave][rr][cc];
        }
        // PV: A-operand (P, cvt to bf16) from LDS, B-operand from vT (contiguous)
        #pragma unroll
        for (int t = 0; t < 2; ++t) {
            bf16x8 ap = cvt8(&psharef[wave][lr][t * 32 + lg * 8]);
            #pragma unroll
            for (int dt = 0; dt < 4; ++dt) {
                const bf16_t* vr = vT + ((size_t)bh * DK + dt * 16 + lr) * S_LEN + n0 + t * 32 + lg * 8;
                ctx[dt] = __builtin_amdgcn_mfma_f32_16x16x32_bf16(ap, ld8(vr), ctx[dt], 0, 0, 0);
            }
        }
        __syncthreads();
    }
    // ctx -> (B, S, 1024) bf16
    #pragma unroll
    for (int dt = 0; dt < 4; ++dt) {
        #pragma unroll
        for (int r = 0; r < 4; ++r) {
            size_t row = (size_t)b * S_LEN + q0 + lg * 4 + r;
            int col = h * DK + dt * 16 + lr;
            ctx_out[row * DMODEL + col] = (bf16_t)ctx[dt][r];
        }
    }
}

// ---------------- residual + LayerNorm (fp32 in/out) ----------------
__global__ __launch_bounds__(256) void ln_kernel(
    const bf16_t* __restrict__ proj, const float* __restrict__ Qres,
    const float* __restrict__ gamma, const float* __restrict__ beta,
    float* __restrict__ y)
{
    __shared__ float red[8];
    int row = blockIdx.x;
    int tid = threadIdx.x;
    int lane = tid & 63, wave = tid >> 6;
    const bf16_t* pr = proj + (size_t)row * DMODEL;
    const float*  qr = Qres + (size_t)row * DMODEL;
    float x[4];
    float sum = 0.f, sumsq = 0.f;
    #pragma unroll
    for (int i = 0; i < 4; ++i) {
        int c = tid + i * 256;
        float v = (float)pr[c] + qr[c];
        x[i] = v; sum += v; sumsq += v * v;
    }
    #pragma unroll
    for (int off = 1; off < 64; off <<= 1) {
        sum += __shfl_xor(sum, off, 64);
        sumsq += __shfl_xor(sumsq, off, 64);
    }
    if (lane == 0) { red[wave] = sum; red[4 + wave] = sumsq; }
    __syncthreads();
    sum = red[0] + red[1] + red[2] + red[3];
    sumsq = red[4] + red[5] + red[6] + red[7];
    float mu = sum * (1.f / DMODEL);
    float var = sumsq * (1.f / DMODEL) - mu * mu;
    float rstd = rsqrtf(var + 1e-5f);
    #pragma unroll
    for (int i = 0; i < 4; ++i) {
        int c = tid + i * 256;
        y[(size_t)row * DMODEL + c] = (x[i] - mu) * rstd * gamma[c] + beta[c];
    }
}

extern "C" void kernel_launch(void* const* d_in, const int* in_sizes, int n_in,
                              void* d_out, int out_size, void* d_ws, size_t ws_size,
                              hipStream_t stream) {
    (void)in_sizes; (void)n_in; (void)out_size; (void)ws_size;
    const float* Q   = (const float*)d_in[0];
    const float* Kin = (const float*)d_in[1];
    const float* Vin = (const float*)d_in[2];
    const int*   mask= (const int*)d_in[3];
    const float* Wq  = (const float*)d_in[4];
    const float* bq  = (const float*)d_in[5];
    const float* Wk  = (const float*)d_in[6];
    const float* bk  = (const float*)d_in[7];
    const float* Wv  = (const float*)d_in[8];
    const float* bv  = (const float*)d_in[9];
    const float* Wo  = (const float*)d_in[10];
    const float* bo  = (const float*)d_in[11];
    const float* lng = (const float*)d_in[12];
    const float* lnb = (const float*)d_in[13];

    const size_t NE = (size_t)BATCH * S_LEN * DMODEL;   // 8,388,608
    const size_t WN = (size_t)DMODEL * DMODEL;          // 1,048,576
    bf16_t* wqb  = (bf16_t*)d_ws;          // 4 converted weights (bf16)
    bf16_t* wkb  = wqb + WN;
    bf16_t* wvb  = wkb + WN;
    bf16_t* wob  = wvb + WN;
    bf16_t* qbuf = wob + WN;               // (B,H,S,64)
    bf16_t* kbuf = qbuf + NE;              // (B,H,S,64)
    bf16_t* vtbuf= kbuf + NE;              // (B,H,64,S)
    bf16_t* ctxbuf = vtbuf + NE;           // (B,S,1024)
    bf16_t* outbuf = qbuf;                 // reuse: qbuf dead after attn
    unsigned long long* mbits = (unsigned long long*)(ctxbuf + NE);  // (B,S,S/64)

    float* y_out    = (float*)d_out;
    float* attn_out = y_out + NE;

    cvt_kernel<<<WN / 2048, 256, 0, stream>>>(Wq, wqb);
    cvt_kernel<<<WN / 2048, 256, 0, stream>>>(Wk, wkb);
    cvt_kernel<<<WN / 2048, 256, 0, stream>>>(Wv, wvb);
    cvt_kernel<<<WN / 2048, 256, 0, stream>>>(Wo, wob);

    const int mask_elems = BATCH * S_LEN * S_LEN;       // 16,777,216
    pack_mask_kernel<<<mask_elems / 256, 256, 0, stream>>>(mask, mbits);

    dim3 gg(BATCH * S_LEN / 64, DMODEL / 64);           // (128, 16)
    gemm_proj<true><<<gg, 256, 0, stream>>>(Q,   wqb, bq, qbuf,  0);
    gemm_proj<true><<<gg, 256, 0, stream>>>(Kin, wkb, bk, kbuf,  0);
    gemm_proj<true><<<gg, 256, 0, stream>>>(Vin, wvb, bv, vtbuf, 1);

    attn_kernel<<<BATCH * NHEADS * (S_LEN / 64), 256, 0, stream>>>(
        qbuf, kbuf, vtbuf, mbits, attn_out, ctxbuf);

    gemm_proj<false><<<gg, 256, 0, stream>>>(ctxbuf, wob, bo, outbuf, 2);

    ln_kernel<<<BATCH * S_LEN, 256, 0, stream>>>(outbuf, Q, lng, lnb, y_out);
}